// Round 2
// baseline (6928.899 us; speedup 1.0000x reference)
//
#include <hip/hip_runtime.h>
#include <hip/hip_bf16.h>

namespace {

constexpr int B_ = 256, V_ = 16, T_ = 64, P_ = 24, F_ = 8, H_ = 256, G_ = 1024;

__device__ __forceinline__ float sigm(float x) { return 1.0f / (1.0f + __expf(-x)); }
__device__ __forceinline__ float bf2f(unsigned short s) {
  union { unsigned u; float f; } x; x.u = ((unsigned)s) << 16; return x.f;
}

// ---------------- init: zero h0/h1/c, prev = sequence[:,:,T-1,:] ----------------
__global__ void init_kernel(float* __restrict__ h0, float* __restrict__ h1,
                            float* __restrict__ c, float* __restrict__ prev,
                            const float* __restrict__ seq) {
  int idx = blockIdx.x * 256 + threadIdx.x;
  if (idx < B_ * V_ * H_) { h0[idx] = 0.f; h1[idx] = 0.f; c[idx] = 0.f; }
  if (idx < B_ * V_ * F_) {
    // prev layout (V,B,F): idx = v*2048 + b*8 + f
    int v = idx >> 11;
    int rem = idx & 2047;
    int b = rem >> 3, f = rem & 7;
    prev[idx] = seq[(((size_t)b * V_ + v) * T_ + (T_ - 1)) * F_ + f];
  }
}

// ---------------- fused gates GEMM + LSTM pointwise ----------------
// MODE 0: encoder (x = sequence[:,:,t,:], hin/hout = h double buffer, writes enc)
// MODE 1: decoder (x = prev*(mx-mn)+mn, hin = hatt, hout = h, no enc)
// grid 512 = v(16) * btile(8) * colchunk(4); block 256 threads
// tile: 32 batches x 256 gate-outputs (4 gates x 64 cols), K = 256
template <int MODE>
__global__ __launch_bounds__(256) void lstm_step_kernel(
    const float* __restrict__ xin,
    const float* __restrict__ hin,
    float* __restrict__ hout,
    float* __restrict__ cbuf,
    __hip_bfloat16* __restrict__ enc,
    const float* __restrict__ W_ih, const float* __restrict__ W_hh,
    const float* __restrict__ b_ih, const float* __restrict__ b_hh,
    const float* __restrict__ maxv, const float* __restrict__ minv,
    int t)
{
  int bx = blockIdx.x;
  int v = bx >> 5, bt = (bx >> 2) & 7, ch = bx & 3;
  int b0 = bt * 32, c0 = ch * 64;
  int tid = threadIdx.x;
  int ty = tid >> 5, tx = tid & 31;
  int q = tx >> 3;  // gate index 0..3 (i,f,g,o)

  __shared__ float hs[16][36];    // [k][b_local]
  __shared__ float ws[16][260];   // [k][n_local]
  __shared__ float xs[32][8];
  __shared__ float wis[256][8];
  __shared__ float bsum[256];

  // stage x (32 b x 8 f)
  {
    int b_l = tid >> 3, f = tid & 7;
    int b = b0 + b_l;
    float xv;
    if (MODE == 0) {
      xv = xin[(((size_t)b * V_ + v) * T_ + t) * F_ + f];
    } else {
      float mx = maxv[b * F_ + f], mn = minv[b * F_ + f];
      xv = xin[((size_t)v * B_ + b) * F_ + f] * (mx - mn) + mn;
    }
    xs[b_l][f] = xv;
  }
  // stage W_ih rows + fused bias (256 block-cols)
  {
    int n = tid;
    int row = ((n >> 6) << 8) + c0 + (n & 63);
    const float* wp = W_ih + ((size_t)v * G_ + row) * F_;
    float4 w0 = *(const float4*)wp;
    float4 w1 = *(const float4*)(wp + 4);
    wis[n][0]=w0.x; wis[n][1]=w0.y; wis[n][2]=w0.z; wis[n][3]=w0.w;
    wis[n][4]=w1.x; wis[n][5]=w1.y; wis[n][6]=w1.z; wis[n][7]=w1.w;
    bsum[n] = b_ih[v*G_ + row] + b_hh[v*G_ + row];
  }

  float acc[4][8];
  #pragma unroll
  for (int r = 0; r < 4; ++r)
    #pragma unroll
    for (int u = 0; u < 8; ++u) acc[r][u] = 0.f;

  for (int kc = 0; kc < H_; kc += 16) {
    __syncthreads();
    {
      int b_l = tid >> 3, kg = tid & 7;
      const float* hp = hin + ((size_t)v * B_ + b0 + b_l) * H_ + kc + kg * 2;
      float2 hv = *(const float2*)hp;
      hs[kg*2+0][b_l] = hv.x;
      hs[kg*2+1][b_l] = hv.y;
    }
    #pragma unroll
    for (int pass = 0; pass < 2; ++pass) {
      int n_l = pass * 128 + (tid >> 1);
      int kh = tid & 1;
      int row = ((n_l >> 6) << 8) + c0 + (n_l & 63);
      const float* wp = W_hh + ((size_t)v * G_ + row) * H_ + kc + kh * 8;
      float4 w0 = *(const float4*)wp;
      float4 w1 = *(const float4*)(wp + 4);
      ws[kh*8+0][n_l]=w0.x; ws[kh*8+1][n_l]=w0.y; ws[kh*8+2][n_l]=w0.z; ws[kh*8+3][n_l]=w0.w;
      ws[kh*8+4][n_l]=w1.x; ws[kh*8+5][n_l]=w1.y; ws[kh*8+6][n_l]=w1.z; ws[kh*8+7][n_l]=w1.w;
    }
    __syncthreads();
    #pragma unroll
    for (int k = 0; k < 16; ++k) {
      float4 a   = *(const float4*)&hs[k][ty * 4];
      float4 bb0 = *(const float4*)&ws[k][tx * 8];
      float4 bb1 = *(const float4*)&ws[k][tx * 8 + 4];
      float av[4] = {a.x, a.y, a.z, a.w};
      float bv[8] = {bb0.x, bb0.y, bb0.z, bb0.w, bb1.x, bb1.y, bb1.z, bb1.w};
      #pragma unroll
      for (int r = 0; r < 4; ++r)
        #pragma unroll
        for (int u = 0; u < 8; ++u)
          acc[r][u] = fmaf(av[r], bv[u], acc[r][u]);
    }
  }

  // add W_ih*x + bias (fold into acc)
  #pragma unroll
  for (int u = 0; u < 8; ++u) {
    int n = tx * 8 + u;
    float wrow[8];
    #pragma unroll
    for (int f = 0; f < 8; ++f) wrow[f] = wis[n][f];
    float bs = bsum[n];
    #pragma unroll
    for (int r = 0; r < 4; ++r) {
      float s = acc[r][u] + bs;
      #pragma unroll
      for (int f = 0; f < 8; ++f) s = fmaf(wrow[f], xs[ty*4+r][f], s);
      acc[r][u] = s;
    }
  }

  // cross-gate exchange (wave shuffle) + LSTM pointwise
  int lane = tid & 63;
  int g0 = (lane & 32) | (tx & 7);
  #pragma unroll
  for (int r = 0; r < 4; ++r) {
    #pragma unroll
    for (int u = 0; u < 8; ++u) {
      float val = acc[r][u];
      float iv = __shfl(val, g0 + 0, 64);
      float fv = __shfl(val, g0 + 8, 64);
      float gv = __shfl(val, g0 + 16, 64);
      float ov = __shfl(val, g0 + 24, 64);
      if (q == r) {
        int b = b0 + ty * 4 + r;
        int j = c0 + (tx & 7) * 8 + u;
        size_t idx = ((size_t)v * B_ + b) * H_ + j;
        float cold = cbuf[idx];
        float cn = sigm(fv) * cold + sigm(iv) * tanhf(gv);
        float hn = sigm(ov) * tanhf(cn);
        cbuf[idx] = cn;
        hout[idx] = hn;
        if (MODE == 0)
          enc[(((size_t)v * B_ + b) * T_ + t) * H_ + j] = __float2bfloat16(hn);
      }
    }
  }
}

// ---------------- decoder attention: score -> softmax -> cv (fused) ----------------
// one block per (v,b); grid = V*B
__global__ __launch_bounds__(256) void attn_kernel(
    const __hip_bfloat16* __restrict__ enc, const float* __restrict__ h,
    const float* __restrict__ mask, float* __restrict__ cv)
{
  int bx = blockIdx.x;
  int v = bx >> 8, b = bx & 255;
  int tid = threadIdx.x;
  __shared__ float hh[H_];
  __shared__ float ss[T_];
  hh[tid] = h[((size_t)v * B_ + b) * H_ + tid];
  __syncthreads();

  int t = tid >> 2, part = tid & 3;
  const __hip_bfloat16* ep = enc + (((size_t)v * B_ + b) * T_ + t) * H_ + part * 64;
  float acc = 0.f;
  #pragma unroll
  for (int it = 0; it < 8; ++it) {
    uint4 uu = *(const uint4*)(ep + it * 8);
    const float* hp = &hh[part * 64 + it * 8];
    acc = fmaf(bf2f((unsigned short)(uu.x & 0xffff)), hp[0], acc);
    acc = fmaf(bf2f((unsigned short)(uu.x >> 16)),    hp[1], acc);
    acc = fmaf(bf2f((unsigned short)(uu.y & 0xffff)), hp[2], acc);
    acc = fmaf(bf2f((unsigned short)(uu.y >> 16)),    hp[3], acc);
    acc = fmaf(bf2f((unsigned short)(uu.z & 0xffff)), hp[4], acc);
    acc = fmaf(bf2f((unsigned short)(uu.z >> 16)),    hp[5], acc);
    acc = fmaf(bf2f((unsigned short)(uu.w & 0xffff)), hp[6], acc);
    acc = fmaf(bf2f((unsigned short)(uu.w >> 16)),    hp[7], acc);
  }
  acc += __shfl_xor(acc, 1, 64);
  acc += __shfl_xor(acc, 2, 64);
  if (part == 0) ss[t] = acc * mask[((size_t)b * V_ + v) * T_ + t];
  __syncthreads();

  if (tid < 64) {
    float s = ss[tid];
    float m = s;
    #pragma unroll
    for (int d = 32; d >= 1; d >>= 1) m = fmaxf(m, __shfl_xor(m, d, 64));
    float e = __expf(s - m);
    float se = e;
    #pragma unroll
    for (int d = 32; d >= 1; d >>= 1) se += __shfl_xor(se, d, 64);
    ss[tid] = e / se;
  }
  __syncthreads();

  int j = tid;
  float a = 0.f;
  const __hip_bfloat16* ecol = enc + (((size_t)v * B_ + b) * T_) * H_ + j;
  #pragma unroll 8
  for (int tt = 0; tt < T_; ++tt)
    a = fmaf(ss[tt], bf2f(*(const unsigned short*)(ecol + (size_t)tt * H_)), a);
  cv[((size_t)v * B_ + b) * H_ + j] = a;
}

// ---------------- h_att = tanh(W_att . cat + b_att) ----------------
// cat(v,b') is CONTIGUOUS: b'<128 -> &cv[v, 2b', 0] (512 floats), else &h[v, 2(b'-128), 0]
// grid 512 = v(16) * btile(16) * nhalf(2); tile 16 b' x 128 n, K=512
__global__ __launch_bounds__(256) void att_gemm_kernel(
    const float* __restrict__ cv, const float* __restrict__ h,
    const float* __restrict__ W_att, const float* __restrict__ b_att,
    float* __restrict__ hatt)
{
  int bx = blockIdx.x;
  int v = bx >> 5, bt = (bx >> 1) & 15, nh = bx & 1;
  int bp0 = bt * 16, n0 = nh * 128;
  int tid = threadIdx.x, ty = tid >> 5, tx = tid & 31;
  __shared__ float hs[16][20];
  __shared__ float ws[16][132];
  float acc[2][4] = {{0.f,0.f,0.f,0.f},{0.f,0.f,0.f,0.f}};

  for (int kc = 0; kc < 2 * H_; kc += 16) {
    __syncthreads();
    {
      int b_l = tid >> 4, kg = tid & 15;
      int bp = bp0 + b_l;
      const float* src = (bp < 128) ? (cv + ((size_t)v * B_ + 2 * bp) * H_)
                                    : (h  + ((size_t)v * B_ + 2 * (bp - 128)) * H_);
      hs[kg][b_l] = src[kc + kg];
    }
    {
      int n_l = tid >> 1, kh = tid & 1;
      const float* wp = W_att + ((size_t)v * H_ + n0 + n_l) * (2 * H_) + kc + kh * 8;
      float4 w0 = *(const float4*)wp, w1 = *(const float4*)(wp + 4);
      ws[kh*8+0][n_l]=w0.x; ws[kh*8+1][n_l]=w0.y; ws[kh*8+2][n_l]=w0.z; ws[kh*8+3][n_l]=w0.w;
      ws[kh*8+4][n_l]=w1.x; ws[kh*8+5][n_l]=w1.y; ws[kh*8+6][n_l]=w1.z; ws[kh*8+7][n_l]=w1.w;
    }
    __syncthreads();
    #pragma unroll
    for (int k = 0; k < 16; ++k) {
      float a0 = hs[k][ty*2+0], a1 = hs[k][ty*2+1];
      float4 bb = *(const float4*)&ws[k][tx*4];
      acc[0][0]=fmaf(a0,bb.x,acc[0][0]); acc[0][1]=fmaf(a0,bb.y,acc[0][1]);
      acc[0][2]=fmaf(a0,bb.z,acc[0][2]); acc[0][3]=fmaf(a0,bb.w,acc[0][3]);
      acc[1][0]=fmaf(a1,bb.x,acc[1][0]); acc[1][1]=fmaf(a1,bb.y,acc[1][1]);
      acc[1][2]=fmaf(a1,bb.z,acc[1][2]); acc[1][3]=fmaf(a1,bb.w,acc[1][3]);
    }
  }
  #pragma unroll
  for (int rr = 0; rr < 2; ++rr) {
    int bp = bp0 + ty * 2 + rr;
    #pragma unroll
    for (int u = 0; u < 4; ++u) {
      int n = n0 + tx * 4 + u;
      hatt[((size_t)v * B_ + bp) * H_ + n] = tanhf(acc[rr][u] + b_att[v * H_ + n]);
    }
  }
}

// ---------------- output projection + clip + prev update ----------------
__global__ __launch_bounds__(256) void out_kernel(
    const float* __restrict__ h, const float* __restrict__ W_out,
    const float* __restrict__ b_out, float* __restrict__ prev,
    float* __restrict__ out, int p)
{
  int gid = blockIdx.x * 256 + threadIdx.x;   // B*V*F = 32768
  int row = gid >> 3;   // v*B + b
  int f = gid & 7;
  int v = row >> 8, b = row & 255;
  const float* hp = h + (size_t)row * H_;
  const float* wp = W_out + f * H_;
  float acc = 0.f;
  #pragma unroll 8
  for (int k = 0; k < H_; k += 4) {
    float4 hv = *(const float4*)(hp + k);
    float4 wv = *(const float4*)(wp + k);
    acc += hv.x*wv.x + hv.y*wv.y + hv.z*wv.z + hv.w*wv.w;
  }
  float o = fmaxf(acc + b_out[f], 0.f);
  prev[gid] = o;  // (v*B+b)*F + f
  if (f < 4)
    out[(((size_t)b * V_ + v) * P_ + p) * 4 + f] = fminf(o, 1.f);
}

}  // namespace

extern "C" void kernel_launch(void* const* d_in, const int* in_sizes, int n_in,
                              void* d_out, int out_size, void* d_ws, size_t ws_size,
                              hipStream_t stream)
{
  const float* seq   = (const float*)d_in[0];
  const float* smask = (const float*)d_in[4];
  const float* maxv  = (const float*)d_in[5];
  const float* minv  = (const float*)d_in[6];
  const float* W_ih  = (const float*)d_in[7];
  const float* W_hh  = (const float*)d_in[8];
  const float* b_ih  = (const float*)d_in[9];
  const float* b_hh  = (const float*)d_in[10];
  const float* W_att = (const float*)d_in[11];
  const float* b_att = (const float*)d_in[12];
  const float* W_out = (const float*)d_in[13];
  const float* b_out = (const float*)d_in[14];
  float* out = (float*)d_out;

  float* wsf = (float*)d_ws;
  const size_t SZ = (size_t)B_ * V_ * H_;
  float* h0   = wsf;
  float* h1   = h0 + SZ;
  float* c    = h1 + SZ;
  float* cvb  = c + SZ;
  float* hatt = cvb + SZ;
  float* prev = hatt + SZ;
  __hip_bfloat16* enc = (__hip_bfloat16*)(prev + (size_t)B_ * V_ * F_);

  init_kernel<<<dim3((B_ * V_ * H_ + 255) / 256), 256, 0, stream>>>(h0, h1, c, prev, seq);

  float* hb[2] = {h0, h1};
  for (int t = 0; t < T_; ++t) {
    lstm_step_kernel<0><<<512, 256, 0, stream>>>(seq, hb[t & 1], hb[(t + 1) & 1], c, enc,
        W_ih, W_hh, b_ih, b_hh, nullptr, nullptr, t);
  }
  float* hF = hb[T_ & 1];  // final encoder h (== h0)
  for (int p = 0; p < P_; ++p) {
    attn_kernel<<<V_ * B_, 256, 0, stream>>>(enc, hF, smask, cvb);
    att_gemm_kernel<<<512, 256, 0, stream>>>(cvb, hF, W_att, b_att, hatt);
    lstm_step_kernel<1><<<512, 256, 0, stream>>>(prev, hatt, hF, c, nullptr,
        W_ih, W_hh, b_ih, b_hh, maxv, minv, 0);
    out_kernel<<<(B_ * V_ * F_) / 256, 256, 0, stream>>>(hF, W_out, b_out, prev, out, p);
  }
}

// Round 6
// 3557.896 us; speedup vs baseline: 1.9475x; 1.9475x over previous
//
#include <hip/hip_runtime.h>
#include <hip/hip_bf16.h>

namespace {

typedef unsigned short u16;
constexpr int B_ = 256, V_ = 16, T_ = 64, P_ = 24, F_ = 8, H_ = 256, G_ = 1024;

typedef __attribute__((ext_vector_type(8))) short bf16x8;
typedef __attribute__((ext_vector_type(4))) float f32x4;

__device__ __forceinline__ float sigm(float x) { return 1.0f / (1.0f + __expf(-x)); }
__device__ __forceinline__ float bf2f(u16 s) {
  union { unsigned u; float f; } x; x.u = ((unsigned)s) << 16; return x.f;
}
__device__ __forceinline__ u16 f2bf(float f) {
  union { float f; unsigned u; } x; x.f = f;
  unsigned r = x.u + 0x7fffu + ((x.u >> 16) & 1u);
  return (u16)(r >> 16);
}
// split fp32 -> bf16 hi/lo pair (hi+lo carries ~16 mantissa bits)
__device__ __forceinline__ void split2(float w, u16& hi, u16& lo) {
  hi = f2bf(w);
  lo = f2bf(w - bf2f(hi));
}
__device__ __forceinline__ void load16(const void* g, void* l) {
  __builtin_amdgcn_global_load_lds(
      (const __attribute__((address_space(1))) unsigned*)g,
      (__attribute__((address_space(3))) unsigned*)l, 16, 0, 0);
}
__device__ __forceinline__ f32x4 mfma16(bf16x8 a, bf16x8 b, f32x4 c) {
  return __builtin_amdgcn_mfma_f32_16x16x32_bf16(a, b, c, 0, 0, 0);
}

// ---------------- init: zero c, prev = sequence[:,:,T-1,:] ----------------
__global__ void init_kernel(float* __restrict__ c, float* __restrict__ prev,
                            const float* __restrict__ seq) {
  int idx = blockIdx.x * 256 + threadIdx.x;          // 262144 threads
  if (idx < B_ * V_ * H_ / 4) ((float4*)c)[idx] = float4{0.f, 0.f, 0.f, 0.f};
  if (idx < B_ * V_ * F_ / 4) {
    // prev (V,B,F): f4 idx = v*512 + b*2 + (f>>2)
    int v = idx >> 9, rem = idx & 511;
    int b = rem >> 1, fq = rem & 1;
    ((float4*)prev)[idx] = ((const float4*)seq)[(((size_t)b * V_ + v) * T_ + (T_ - 1)) * 2 + fq];
  }
}

// ---------------- convert W_hh, W_att fp32 -> bf16 hi/lo pairs ----------------
__global__ void convert_kernel(const float* __restrict__ Whh, const float* __restrict__ Watt,
                               u16* __restrict__ whhH, u16* __restrict__ whhL,
                               u16* __restrict__ wattH, u16* __restrict__ wattL) {
  int gid = blockIdx.x * 256 + threadIdx.x;
  const int n1 = V_ * G_ * H_ / 4;       // 1048576 float4s
  const int n2 = V_ * H_ * 2 * H_ / 4;   // 524288
  const float* src; u16 *dH, *dL; int i;
  if (gid < n1)            { src = Whh;  dH = whhH;  dL = whhL;  i = gid; }
  else if (gid < n1 + n2)  { src = Watt; dH = wattH; dL = wattL; i = gid - n1; }
  else return;
  float4 wv = ((const float4*)src)[i];
  u16 h0,l0,h1,l1,h2,l2,h3,l3;
  split2(wv.x,h0,l0); split2(wv.y,h1,l1); split2(wv.z,h2,l2); split2(wv.w,h3,l3);
  uint2 oh; oh.x = (unsigned)h0 | ((unsigned)h1 << 16); oh.y = (unsigned)h2 | ((unsigned)h3 << 16);
  uint2 ol; ol.x = (unsigned)l0 | ((unsigned)l1 << 16); ol.y = (unsigned)l2 | ((unsigned)l3 << 16);
  ((uint2*)dH)[i] = oh; ((uint2*)dL)[i] = ol;
}

// ---------------- copy final encoder h -> hdec (hi from enc t=63, lo from hlo[1]) ----------------
__global__ void copy_h_kernel(const u16* __restrict__ enc, const u16* __restrict__ hlo1,
                              u16* __restrict__ hdecHi, u16* __restrict__ hdecLo) {
  int gid = blockIdx.x * 256 + threadIdx.x;   // 131072 uint4s
  int row = gid >> 5, jq = gid & 31;
  ((uint4*)hdecHi)[gid] = ((const uint4*)enc)[((size_t)row * T_ + (T_ - 1)) * 32 + jq];
  ((uint4*)hdecLo)[gid] = ((const uint4*)hlo1)[gid];
}

// ---------------- fused split-MFMA gates GEMM + LSTM pointwise ----------------
// gates = (Ah+Al)(Wh+Wl)^T ~= Ah.Wh + Al.Wh + Ah.Wl  (3-term split product)
// MODE 0: encoder. A = h(t-1) pair (enc slice + hloIn); out h(t) -> enc slice + hloOut.
// MODE 1: decoder. A = hatt pair; out -> hdecHi/Lo. x = prev*(mx-mn)+mn.
// grid 1024 = v(16) x btile(8) x ch(8). block 256 = 4 waves.
// block tile: 32 b x 128 gate-cols (gc = gate*32 + cc -> G-row gate*256 + c0 + cc).
// K = 256, 8 k-steps of 32, double-buffered global_load_lds staging.
// 64B LDS rows, XOR-swizzle granule16 with ((row>>1)&3) (2-way residual = free).
// Swizzle on SOURCE addr + READ addr, LDS dest linear (rule #21).
template <int MODE>
__global__ __launch_bounds__(256) void lstm_mfma_kernel(
    const float* __restrict__ xin,        // MODE0: sequence, MODE1: prev
    u16* __restrict__ enc,                // MODE0: in (t-1) / out (t)
    const u16* __restrict__ hloIn,        // MODE0: lo of h(t-1)
    u16* __restrict__ hloOut,             // MODE0: lo of h(t)
    const u16* __restrict__ aHi,          // MODE1: hatt hi
    const u16* __restrict__ aLo,          // MODE1: hatt lo
    u16* __restrict__ hdecHi, u16* __restrict__ hdecLo,   // MODE1 out
    float* __restrict__ cbuf,
    const u16* __restrict__ WhhHi, const u16* __restrict__ WhhLo,
    const float* __restrict__ W_ih, const float* __restrict__ b_ih,
    const float* __restrict__ b_hh,
    const float* __restrict__ maxv, const float* __restrict__ minv,
    int t)
{
  __shared__ char smem[46592];
  // A_hi [0,4096) A_lo [4096,8192) B_hi [8192,24576) B_lo [24576,40960)  (2 bufs each)
  // gates aliases [0, 17024) = 32 x 133 fl.  xs@40960  wis@41984  bsum@46080
  float* gates = (float*)smem;
  float* xsf   = (float*)(smem + 40960);
  float* wisf  = (float*)(smem + 41984);
  float* bsumf = (float*)(smem + 46080);

  int bx = blockIdx.x;
  int v = bx >> 6, bt = (bx >> 3) & 7, ch = bx & 7;
  int b0 = bt * 32, c0 = ch * 32;
  int tid = threadIdx.x, lane = tid & 63, w = tid >> 6;

  // ---- stage x (32 b x 8 f) ----
  {
    int b_l = tid >> 3, f = tid & 7;
    int b = b0 + b_l;
    float xv;
    if (MODE == 0) {
      xv = xin[(((size_t)b * V_ + v) * T_ + t) * F_ + f];
    } else {
      float mx = maxv[b * F_ + f], mn = minv[b * F_ + f];
      xv = xin[((size_t)v * B_ + b) * F_ + f] * (mx - mn) + mn;
    }
    xsf[b_l * 8 + f] = xv;
  }
  // ---- stage W_ih rows + fused bias for the 128 block gate-cols ----
  if (tid < 128) {
    int gc = tid;
    int grow = ((gc >> 5) << 8) + c0 + (gc & 31);
    const float* wp = W_ih + ((size_t)v * G_ + grow) * F_;
    *(float4*)(wisf + gc * 8)     = *(const float4*)wp;
    *(float4*)(wisf + gc * 8 + 4) = *(const float4*)(wp + 4);
    bsumf[gc] = b_ih[v * G_ + grow] + b_hh[v * G_ + grow];
  }

  const bool hasK = (MODE == 1) || (t > 0);

  auto stageAB = [&](int ks, int bufn) {
    int kc = ks * 32;
    // B: 128 gc x 32 k, hi + lo (512 granules each, 2/thread each)
    #pragma unroll
    for (int it = 0; it < 2; ++it) {
      int gb = it * 256 + tid;
      int gc = gb >> 2, g2 = gb & 3;
      int grow = ((gc >> 5) << 8) + c0 + (gc & 31);
      int kb = ((g2 ^ ((gc >> 1) & 3)) << 4);
      size_t off = ((((size_t)v * G_ + grow) * H_ + kc) << 1) + kb;
      load16((const char*)WhhHi + off, smem + 8192  + bufn * 8192 + gb * 16);
      load16((const char*)WhhLo + off, smem + 24576 + bufn * 8192 + gb * 16);
    }
    // A: 32 b x 32 k, hi (waves 0,1) + lo (waves 2,3)
    {
      int g = tid & 127;
      int b = g >> 2, g2 = g & 3;
      int kb = ((g2 ^ ((b >> 1) & 3)) << 4);
      size_t rowoff = (((size_t)(v * B_ + b0 + b)) * H_ + kc) * 2 + kb;
      if (MODE == 0) {
        if (tid < 128)
          load16((const char*)enc + ((((size_t)(v * B_ + b0 + b)) * T_ + (t - 1)) * H_ + kc) * 2 + kb,
                 smem + bufn * 2048 + g * 16);
        else
          load16((const char*)hloIn + rowoff, smem + 4096 + bufn * 2048 + g * 16);
      } else {
        if (tid < 128)
          load16((const char*)aHi + rowoff, smem + bufn * 2048 + g * 16);
        else
          load16((const char*)aLo + rowoff, smem + 4096 + bufn * 2048 + g * 16);
      }
    }
  };

  f32x4 acc[2][2];
  #pragma unroll
  for (int i = 0; i < 2; ++i)
    #pragma unroll
    for (int j = 0; j < 2; ++j) acc[i][j] = f32x4{0.f, 0.f, 0.f, 0.f};

  if (hasK) stageAB(0, 0);
  __syncthreads();   // also covers xs/wis

  if (hasK) {
    int rA = lane & 15, kg = lane >> 4;
    int aoff0 = rA * 64 + ((kg ^ ((rA >> 1) & 3)) << 4);
    int gc0 = w * 32 + rA;
    int boff0 = gc0 * 64 + ((kg ^ ((gc0 >> 1) & 3)) << 4);
    int buf = 0;
    for (int ks = 0; ks < 8; ++ks) {
      if (ks < 7) stageAB(ks + 1, buf ^ 1);
      const char* Ah = smem + buf * 2048;
      const char* Al = smem + 4096  + buf * 2048;
      const char* Bh = smem + 8192  + buf * 8192;
      const char* Bl = smem + 24576 + buf * 8192;
      bf16x8 ah0 = *(const bf16x8*)(Ah + aoff0);
      bf16x8 ah1 = *(const bf16x8*)(Ah + aoff0 + 1024);
      bf16x8 al0 = *(const bf16x8*)(Al + aoff0);
      bf16x8 al1 = *(const bf16x8*)(Al + aoff0 + 1024);
      bf16x8 bh0 = *(const bf16x8*)(Bh + boff0);
      bf16x8 bh1 = *(const bf16x8*)(Bh + boff0 + 1024);
      bf16x8 bl0 = *(const bf16x8*)(Bl + boff0);
      bf16x8 bl1 = *(const bf16x8*)(Bl + boff0 + 1024);
      acc[0][0] = mfma16(ah0, bh0, acc[0][0]);
      acc[0][1] = mfma16(ah0, bh1, acc[0][1]);
      acc[1][0] = mfma16(ah1, bh0, acc[1][0]);
      acc[1][1] = mfma16(ah1, bh1, acc[1][1]);
      acc[0][0] = mfma16(al0, bh0, acc[0][0]);
      acc[0][1] = mfma16(al0, bh1, acc[0][1]);
      acc[1][0] = mfma16(al1, bh0, acc[1][0]);
      acc[1][1] = mfma16(al1, bh1, acc[1][1]);
      acc[0][0] = mfma16(ah0, bl0, acc[0][0]);
      acc[0][1] = mfma16(ah0, bl1, acc[0][1]);
      acc[1][0] = mfma16(ah1, bl0, acc[1][0]);
      acc[1][1] = mfma16(ah1, bl1, acc[1][1]);
      __syncthreads();
      buf ^= 1;
    }
  }

  // ---- epilogue: + W_ih*x + bias, gates -> LDS ----
  {
    int rA = lane & 15, rowg = (lane >> 4) * 4;
    #pragma unroll
    for (int i = 0; i < 2; ++i)
      #pragma unroll
      for (int j = 0; j < 2; ++j) {
        int gc = w * 32 + j * 16 + rA;
        float bs = bsumf[gc];
        float wr[8];
        #pragma unroll
        for (int f = 0; f < 8; ++f) wr[f] = wisf[gc * 8 + f];
        #pragma unroll
        for (int r = 0; r < 4; ++r) {
          int b_l = i * 16 + rowg + r;
          float s = acc[i][j][r] + bs;
          #pragma unroll
          for (int f = 0; f < 8; ++f) s = fmaf(wr[f], xsf[b_l * 8 + f], s);
          gates[b_l * 133 + gc] = s;
        }
      }
  }
  __syncthreads();

  // ---- LSTM pointwise: 4 outputs per thread ----
  {
    int b_l = tid >> 3, cc0 = (tid & 7) * 4;
    #pragma unroll
    for (int u = 0; u < 4; ++u) {
      int cc = cc0 + u;
      float iv = gates[b_l * 133 + cc];
      float fv = gates[b_l * 133 + 32 + cc];
      float gv = gates[b_l * 133 + 64 + cc];
      float ov = gates[b_l * 133 + 96 + cc];
      size_t gidx = ((size_t)(v * B_ + b0 + b_l)) * H_ + c0 + cc;
      float cold = cbuf[gidx];
      float cn = sigm(fv) * cold + sigm(iv) * tanhf(gv);
      float hn = sigm(ov) * tanhf(cn);
      cbuf[gidx] = cn;
      u16 hi, lo; split2(hn, hi, lo);
      if (MODE == 0) {
        enc[(((size_t)(v * B_ + b0 + b_l)) * T_ + t) * H_ + c0 + cc] = hi;
        hloOut[gidx] = lo;
      } else {
        hdecHi[gidx] = hi;
        hdecLo[gidx] = lo;
      }
    }
  }
}

// ---------------- decoder attention: score -> softmax -> cv ----------------
__global__ __launch_bounds__(256) void attn_kernel(
    const u16* __restrict__ enc, const u16* __restrict__ hHi, const u16* __restrict__ hLo,
    const float* __restrict__ mask, u16* __restrict__ cvHi, u16* __restrict__ cvLo)
{
  int bx = blockIdx.x;
  int v = bx >> 8, b = bx & 255;
  int tid = threadIdx.x;
  __shared__ float hh[H_];
  __shared__ float ss[T_];
  {
    size_t hidx = ((size_t)v * B_ + b) * H_ + tid;
    hh[tid] = bf2f(hHi[hidx]) + bf2f(hLo[hidx]);
  }
  __syncthreads();

  int t = tid >> 2, part = tid & 3;
  const u16* ep = enc + (((size_t)(v * B_ + b)) * T_ + t) * H_ + part * 64;
  float acc = 0.f;
  #pragma unroll
  for (int it = 0; it < 8; ++it) {
    uint4 uu = *(const uint4*)(ep + it * 8);
    const float* hp = &hh[part * 64 + it * 8];
    acc = fmaf(bf2f((u16)(uu.x & 0xffff)), hp[0], acc);
    acc = fmaf(bf2f((u16)(uu.x >> 16)),    hp[1], acc);
    acc = fmaf(bf2f((u16)(uu.y & 0xffff)), hp[2], acc);
    acc = fmaf(bf2f((u16)(uu.y >> 16)),    hp[3], acc);
    acc = fmaf(bf2f((u16)(uu.z & 0xffff)), hp[4], acc);
    acc = fmaf(bf2f((u16)(uu.z >> 16)),    hp[5], acc);
    acc = fmaf(bf2f((u16)(uu.w & 0xffff)), hp[6], acc);
    acc = fmaf(bf2f((u16)(uu.w >> 16)),    hp[7], acc);
  }
  acc += __shfl_xor(acc, 1, 64);
  acc += __shfl_xor(acc, 2, 64);
  if (part == 0) ss[t] = acc * mask[((size_t)b * V_ + v) * T_ + t];
  __syncthreads();

  if (tid < 64) {
    float s = ss[tid];
    float m = s;
    #pragma unroll
    for (int d = 32; d >= 1; d >>= 1) m = fmaxf(m, __shfl_xor(m, d, 64));
    float e = __expf(s - m);
    float se = e;
    #pragma unroll
    for (int d = 32; d >= 1; d >>= 1) se += __shfl_xor(se, d, 64);
    ss[tid] = e / se;
  }
  __syncthreads();

  int j = tid;
  float a = 0.f;
  const u16* ecol = enc + (((size_t)(v * B_ + b)) * T_) * H_ + j;
  #pragma unroll 8
  for (int tt = 0; tt < T_; ++tt)
    a = fmaf(ss[tt], bf2f(ecol[(size_t)tt * H_]), a);
  u16 hi, lo; split2(a, hi, lo);
  size_t cidx = ((size_t)v * B_ + b) * H_ + j;
  cvHi[cidx] = hi;
  cvLo[cidx] = lo;
}

// ---------------- h_att = tanh(W_att . cat + b_att), split-MFMA ----------------
// cat row b' (512 bf16, contiguous): b'<128 -> cv[v][2b'..], else hdec[v][2(b'-128)..]
// grid 256 = v(16) x btile(8) x nhalf(2). block tile 32 b' x 128 n; K = 512, 16 k-steps.
__global__ __launch_bounds__(256) void attg_mfma_kernel(
    const u16* __restrict__ cvHi, const u16* __restrict__ cvLo,
    const u16* __restrict__ hdHi, const u16* __restrict__ hdLo,
    const u16* __restrict__ WattHi, const u16* __restrict__ WattLo,
    const float* __restrict__ b_att,
    u16* __restrict__ hattHi, u16* __restrict__ hattLo)
{
  __shared__ char smem[40960];
  // A_hi [0,4096) A_lo [4096,8192) B_hi [8192,24576) B_lo [24576,40960)
  int bx = blockIdx.x;
  int v = bx >> 4, bt = (bx >> 1) & 7, nh = bx & 1;
  int bp0 = bt * 32, n0 = nh * 128;
  int tid = threadIdx.x, lane = tid & 63, w = tid >> 6;

  auto stageAB = [&](int ks, int bufn) {
    int kc = ks * 32;
    #pragma unroll
    for (int it = 0; it < 2; ++it) {
      int gb = it * 256 + tid;
      int nl = gb >> 2, g2 = gb & 3;
      int kb = ((g2 ^ ((nl >> 1) & 3)) << 4);
      size_t off = ((((size_t)v * H_ + n0 + nl) * (2 * H_) + kc) << 1) + kb;
      load16((const char*)WattHi + off, smem + 8192  + bufn * 8192 + gb * 16);
      load16((const char*)WattLo + off, smem + 24576 + bufn * 8192 + gb * 16);
    }
    {
      int g = tid & 127;
      int b = g >> 2, g2 = g & 3;
      int kb = ((g2 ^ ((b >> 1) & 3)) << 4);
      int bp = bp0 + b;
      const u16* baseH = (bp < 128) ? (cvHi + ((size_t)v * B_ + 2 * bp) * H_)
                                    : (hdHi + ((size_t)v * B_ + 2 * (bp - 128)) * H_);
      const u16* baseL = (bp < 128) ? (cvLo + ((size_t)v * B_ + 2 * bp) * H_)
                                    : (hdLo + ((size_t)v * B_ + 2 * (bp - 128)) * H_);
      if (tid < 128) load16((const char*)baseH + kc * 2 + kb, smem + bufn * 2048 + g * 16);
      else           load16((const char*)baseL + kc * 2 + kb, smem + 4096 + bufn * 2048 + g * 16);
    }
  };

  f32x4 acc[2][2];
  #pragma unroll
  for (int i = 0; i < 2; ++i)
    #pragma unroll
    for (int j = 0; j < 2; ++j) acc[i][j] = f32x4{0.f, 0.f, 0.f, 0.f};

  stageAB(0, 0);
  __syncthreads();

  int rA = lane & 15, kg = lane >> 4;
  int aoff0 = rA * 64 + ((kg ^ ((rA >> 1) & 3)) << 4);
  int gc0 = w * 32 + rA;
  int boff0 = gc0 * 64 + ((kg ^ ((gc0 >> 1) & 3)) << 4);
  int buf = 0;
  for (int ks = 0; ks < 16; ++ks) {
    if (ks < 15) stageAB(ks + 1, buf ^ 1);
    const char* Ah = smem + buf * 2048;
    const char* Al = smem + 4096  + buf * 2048;
    const char* Bh = smem + 8192  + buf * 8192;
    const char* Bl = smem + 24576 + buf * 8192;
    bf16x8 ah0 = *(const bf16x8*)(Ah + aoff0);
    bf16x8 ah1 = *(const bf16x8*)(Ah + aoff0 + 1024);
    bf16x8 al0 = *(const bf16x8*)(Al + aoff0);
    bf16x8 al1 = *(const bf16x8*)(Al + aoff0 + 1024);
    bf16x8 bh0 = *(const bf16x8*)(Bh + boff0);
    bf16x8 bh1 = *(const bf16x8*)(Bh + boff0 + 1024);
    bf16x8 bl0 = *(const bf16x8*)(Bl + boff0);
    bf16x8 bl1 = *(const bf16x8*)(Bl + boff0 + 1024);
    acc[0][0] = mfma16(ah0, bh0, acc[0][0]);
    acc[0][1] = mfma16(ah0, bh1, acc[0][1]);
    acc[1][0] = mfma16(ah1, bh0, acc[1][0]);
    acc[1][1] = mfma16(ah1, bh1, acc[1][1]);
    acc[0][0] = mfma16(al0, bh0, acc[0][0]);
    acc[0][1] = mfma16(al0, bh1, acc[0][1]);
    acc[1][0] = mfma16(al1, bh0, acc[1][0]);
    acc[1][1] = mfma16(al1, bh1, acc[1][1]);
    acc[0][0] = mfma16(ah0, bl0, acc[0][0]);
    acc[0][1] = mfma16(ah0, bl1, acc[0][1]);
    acc[1][0] = mfma16(ah1, bl0, acc[1][0]);
    acc[1][1] = mfma16(ah1, bl1, acc[1][1]);
    __syncthreads();
    buf ^= 1;
  }

  int rowg = (lane >> 4) * 4;
  #pragma unroll
  for (int i = 0; i < 2; ++i)
    #pragma unroll
    for (int j = 0; j < 2; ++j) {
      int n = n0 + w * 32 + j * 16 + rA;
      float bias = b_att[v * H_ + n];
      #pragma unroll
      for (int r = 0; r < 4; ++r) {
        int bp = bp0 + i * 16 + rowg + r;
        float tv = tanhf(acc[i][j][r] + bias);
        u16 hi, lo; split2(tv, hi, lo);
        size_t hidx = ((size_t)v * B_ + bp) * H_ + n;
        hattHi[hidx] = hi;
        hattLo[hidx] = lo;
      }
    }
}

// ---------------- output projection + clip + prev update ----------------
__global__ __launch_bounds__(256) void out_kernel(
    const u16* __restrict__ hHi, const u16* __restrict__ hLo,
    const float* __restrict__ W_out, const float* __restrict__ b_out,
    float* __restrict__ prev, float* __restrict__ out, int p)
{
  int gid = blockIdx.x * 256 + threadIdx.x;   // V*B*F = 32768
  int row = gid >> 3;   // v*B + b
  int f = gid & 7;
  int v = row >> 8, b = row & 255;
  const u16* hp = hHi + (size_t)row * H_;
  const u16* lp = hLo + (size_t)row * H_;
  const float* wp = W_out + f * H_;
  float acc = 0.f;
  #pragma unroll 4
  for (int k = 0; k < H_; k += 8) {
    uint4 hv = *(const uint4*)(hp + k);
    uint4 lv = *(const uint4*)(lp + k);
    float4 w0 = *(const float4*)(wp + k);
    float4 w1 = *(const float4*)(wp + k + 4);
    acc = fmaf(bf2f((u16)(hv.x & 0xffff)) + bf2f((u16)(lv.x & 0xffff)), w0.x, acc);
    acc = fmaf(bf2f((u16)(hv.x >> 16))    + bf2f((u16)(lv.x >> 16)),    w0.y, acc);
    acc = fmaf(bf2f((u16)(hv.y & 0xffff)) + bf2f((u16)(lv.y & 0xffff)), w0.z, acc);
    acc = fmaf(bf2f((u16)(hv.y >> 16))    + bf2f((u16)(lv.y >> 16)),    w0.w, acc);
    acc = fmaf(bf2f((u16)(hv.z & 0xffff)) + bf2f((u16)(lv.z & 0xffff)), w1.x, acc);
    acc = fmaf(bf2f((u16)(hv.z >> 16))    + bf2f((u16)(lv.z >> 16)),    w1.y, acc);
    acc = fmaf(bf2f((u16)(hv.w & 0xffff)) + bf2f((u16)(lv.w & 0xffff)), w1.z, acc);
    acc = fmaf(bf2f((u16)(hv.w >> 16))    + bf2f((u16)(lv.w >> 16)),    w1.w, acc);
  }
  float o = fmaxf(acc + b_out[f], 0.f);
  prev[gid] = o;  // (v*B+b)*F + f
  if (f < 4)
    out[(((size_t)b * V_ + v) * P_ + p) * 4 + f] = fminf(o, 1.f);
}

}  // namespace

extern "C" void kernel_launch(void* const* d_in, const int* in_sizes, int n_in,
                              void* d_out, int out_size, void* d_ws, size_t ws_size,
                              hipStream_t stream)
{
  const float* seq   = (const float*)d_in[0];
  const float* smask = (const float*)d_in[4];
  const float* maxv  = (const float*)d_in[5];
  const float* minv  = (const float*)d_in[6];
  const float* W_ih  = (const float*)d_in[7];
  const float* W_hh  = (const float*)d_in[8];
  const float* b_ih  = (const float*)d_in[9];
  const float* b_hh  = (const float*)d_in[10];
  const float* W_att = (const float*)d_in[11];
  const float* b_att = (const float*)d_in[12];
  const float* W_out = (const float*)d_in[13];
  const float* b_out = (const float*)d_in[14];
  float* out = (float*)d_out;

  char* ws = (char*)d_ws;
  float* c     = (float*)(ws);                 //  4,194,304
  float* prev  = (float*)(ws + 4194304);       //    131,072
  u16* h_lo    = (u16*)(ws + 4325376);         //  4,194,304 (2 bufs)
  u16* hdecHi  = (u16*)(ws + 8519680);         //  2,097,152
  u16* hdecLo  = (u16*)(ws + 10616832);        //  2,097,152
  u16* hattHi  = (u16*)(ws + 12713984);        //  2,097,152
  u16* hattLo  = (u16*)(ws + 14811136);        //  2,097,152
  u16* cvHi    = (u16*)(ws + 16908288);        //  2,097,152
  u16* cvLo    = (u16*)(ws + 19005440);        //  2,097,152
  u16* whhHi   = (u16*)(ws + 21102592);        //  8,388,608
  u16* whhLo   = (u16*)(ws + 29491200);        //  8,388,608
  u16* wattHi  = (u16*)(ws + 37879808);        //  4,194,304
  u16* wattLo  = (u16*)(ws + 42074112);        //  4,194,304
  u16* enc     = (u16*)(ws + 46268416);        // 134,217,728   (total ~180.5 MB)

  const size_t SZ = (size_t)V_ * B_ * H_;

  init_kernel<<<1024, 256, 0, stream>>>(c, prev, seq);
  convert_kernel<<<6144, 256, 0, stream>>>(W_hh, W_att, whhHi, whhLo, wattHi, wattLo);

  for (int t = 0; t < T_; ++t) {
    lstm_mfma_kernel<0><<<1024, 256, 0, stream>>>(seq, enc,
        h_lo + ((t + 1) & 1) * SZ, h_lo + (t & 1) * SZ,
        nullptr, nullptr, nullptr, nullptr, c, whhHi, whhLo,
        W_ih, b_ih, b_hh, nullptr, nullptr, t);
  }
  copy_h_kernel<<<512, 256, 0, stream>>>(enc, h_lo + SZ, hdecHi, hdecLo);

  for (int p = 0; p < P_; ++p) {
    attn_kernel<<<V_ * B_, 256, 0, stream>>>(enc, hdecHi, hdecLo, smask, cvHi, cvLo);
    attg_mfma_kernel<<<256, 256, 0, stream>>>(cvHi, cvLo, hdecHi, hdecLo,
        wattHi, wattLo, b_att, hattHi, hattLo);
    lstm_mfma_kernel<1><<<1024, 256, 0, stream>>>(prev, nullptr, nullptr, nullptr,
        hattHi, hattLo, hdecHi, hdecLo, c, whhHi, whhLo,
        W_ih, b_ih, b_hh, maxv, minv, 1);
    out_kernel<<<128, 256, 0, stream>>>(hdecHi, hdecLo, W_out, b_out, prev, out, p);
  }
}

// Round 8
// 2627.510 us; speedup vs baseline: 2.6371x; 1.3541x over previous
//
#include <hip/hip_runtime.h>
#include <hip/hip_bf16.h>

namespace {

typedef unsigned short u16;
constexpr int B_ = 256, V_ = 16, T_ = 64, P_ = 24, F_ = 8, H_ = 256, G_ = 1024;

typedef __attribute__((ext_vector_type(8))) short bf16x8;
typedef __attribute__((ext_vector_type(4))) float f32x4;

__device__ __forceinline__ float sigm(float x) { return 1.0f / (1.0f + __expf(-x)); }
__device__ __forceinline__ float bf2f(u16 s) {
  union { unsigned u; float f; } x; x.u = ((unsigned)s) << 16; return x.f;
}
__device__ __forceinline__ u16 f2bf(float f) {
  union { float f; unsigned u; } x; x.f = f;
  unsigned r = x.u + 0x7fffu + ((x.u >> 16) & 1u);
  return (u16)(r >> 16);
}
// split fp32 -> bf16 hi/lo pair (hi+lo carries ~16 mantissa bits)
__device__ __forceinline__ void split2(float w, u16& hi, u16& lo) {
  hi = f2bf(w);
  lo = f2bf(w - bf2f(hi));
}
__device__ __forceinline__ void load16(const void* g, void* l) {
  __builtin_amdgcn_global_load_lds(
      (const __attribute__((address_space(1))) unsigned*)g,
      (__attribute__((address_space(3))) unsigned*)l, 16, 0, 0);
}
__device__ __forceinline__ f32x4 mfma16(bf16x8 a, bf16x8 b, f32x4 c) {
  return __builtin_amdgcn_mfma_f32_16x16x32_bf16(a, b, c, 0, 0, 0);
}

// ---------------- init: zero c, prev = sequence[:,:,T-1,:] ----------------
__global__ void init_kernel(float* __restrict__ c, float* __restrict__ prev,
                            const float* __restrict__ seq) {
  int idx = blockIdx.x * 256 + threadIdx.x;
  if (idx < B_ * V_ * H_ / 4) ((float4*)c)[idx] = float4{0.f, 0.f, 0.f, 0.f};
  if (idx < B_ * V_ * F_ / 4) {
    int v = idx >> 9, rem = idx & 511;
    int b = rem >> 1, fq = rem & 1;
    ((float4*)prev)[idx] = ((const float4*)seq)[(((size_t)b * V_ + v) * T_ + (T_ - 1)) * 2 + fq];
  }
}

// ---------------- convert W_hh, W_att fp32 -> bf16 hi/lo pairs ----------------
__global__ void convert_kernel(const float* __restrict__ Whh, const float* __restrict__ Watt,
                               u16* __restrict__ whhH, u16* __restrict__ whhL,
                               u16* __restrict__ wattH, u16* __restrict__ wattL) {
  int gid = blockIdx.x * 256 + threadIdx.x;
  const int n1 = V_ * G_ * H_ / 4;       // 1048576 float4s
  const int n2 = V_ * H_ * 2 * H_ / 4;   // 524288
  const float* src; u16 *dH, *dL; int i;
  if (gid < n1)            { src = Whh;  dH = whhH;  dL = whhL;  i = gid; }
  else if (gid < n1 + n2)  { src = Watt; dH = wattH; dL = wattL; i = gid - n1; }
  else return;
  float4 wv = ((const float4*)src)[i];
  u16 h0,l0,h1,l1,h2,l2,h3,l3;
  split2(wv.x,h0,l0); split2(wv.y,h1,l1); split2(wv.z,h2,l2); split2(wv.w,h3,l3);
  uint2 oh; oh.x = (unsigned)h0 | ((unsigned)h1 << 16); oh.y = (unsigned)h2 | ((unsigned)h3 << 16);
  uint2 ol; ol.x = (unsigned)l0 | ((unsigned)l1 << 16); ol.y = (unsigned)l2 | ((unsigned)l3 << 16);
  ((uint2*)dH)[i] = oh; ((uint2*)dL)[i] = ol;
}

// ---------------- copy final encoder h -> hdec ----------------
__global__ void copy_h_kernel(const u16* __restrict__ enc, const u16* __restrict__ hlo1,
                              u16* __restrict__ hdecHi, u16* __restrict__ hdecLo) {
  int gid = blockIdx.x * 256 + threadIdx.x;   // 131072 uint4s
  int row = gid >> 5, jq = gid & 31;
  ((uint4*)hdecHi)[gid] = ((const uint4*)enc)[((size_t)row * T_ + (T_ - 1)) * 32 + jq];
  ((uint4*)hdecLo)[gid] = ((const uint4*)hlo1)[gid];
}

// ---------------- fused split-MFMA gates GEMM + LSTM pointwise (v2) ----------------
// grid 256 = XCD-swizzled (v16 x bt2 x ch8): xcd = bid&7 holds vessels {2xcd, 2xcd+1}
// so each XCD's L2 caches its 2 vessels' Whh hi/lo (2 MB < 4 MB).
// block 512 thr = 8 waves (4 wave-rows x 2 wave-cols). Tile: 128 b x 128 gate-cols.
// Wave: 32 b x 16 cc x 4 gates -> B frags = the 4 gates of the SAME cc -> i,f,g,o
// land in one thread's acc => pointwise fully in registers (no gates LDS).
// K = 256, k-step 32, double-buffered global_load_lds; 64B LDS rows with
// granule16 XOR swizzle ((row>>1)&3) on SOURCE + READ, dest linear (rule #21).
template <int MODE>
__global__ __launch_bounds__(512) void lstm_mfma_kernel(
    const float* __restrict__ xin,        // MODE0: sequence, MODE1: prev
    u16* __restrict__ enc,                // MODE0: in (t-1) / out (t)
    const u16* __restrict__ hloIn,        // MODE0: lo of h(t-1)
    u16* __restrict__ hloOut,             // MODE0: lo of h(t)
    const u16* __restrict__ aHi,          // MODE1: hatt hi
    const u16* __restrict__ aLo,          // MODE1: hatt lo
    u16* __restrict__ hdecHi, u16* __restrict__ hdecLo,   // MODE1 out
    float* __restrict__ cbuf,
    const u16* __restrict__ WhhHi, const u16* __restrict__ WhhLo,
    const float* __restrict__ W_ih, const float* __restrict__ b_ih,
    const float* __restrict__ b_hh,
    const float* __restrict__ maxv, const float* __restrict__ minv,
    int t)
{
  __shared__ char smem[74240];
  // Ah [0,16K) Al [16K,32K) Bh [32K,48K) Bl [48K,64K)   (each: 2 bufs x 8K)
  // xs @65536 (128x8 f32)  wis @69632 (128x8)  bsum @73728 (128)
  float* xsf   = (float*)(smem + 65536);
  float* wisf  = (float*)(smem + 69632);
  float* bsumf = (float*)(smem + 73728);

  int bid = blockIdx.x;
  int xcd = bid & 7, idx = bid >> 3;
  int v  = xcd * 2 + (idx & 1);
  int bt = (idx >> 1) & 1;
  int ch = idx >> 2;                 // 0..7
  int b0 = bt * 128, c0 = ch * 32;
  int tid = threadIdx.x, lane = tid & 63, w = tid >> 6;
  int wr = w >> 1, wc = w & 1;

  // ---- stage x (128 b x 8 f), W_ih rows (128 gc x 8), bias ----
  if (tid < 256) {
    int b_l = tid >> 1, fq = tid & 1;
    int b = b0 + b_l;
    float4 xv;
    if (MODE == 0) {
      xv = *(const float4*)(xin + (((size_t)b * V_ + v) * T_ + t) * F_ + fq * 4);
    } else {
      float4 pv = *(const float4*)(xin + ((size_t)v * B_ + b) * F_ + fq * 4);
      float4 mx = *(const float4*)(maxv + b * F_ + fq * 4);
      float4 mn = *(const float4*)(minv + b * F_ + fq * 4);
      xv.x = pv.x * (mx.x - mn.x) + mn.x;
      xv.y = pv.y * (mx.y - mn.y) + mn.y;
      xv.z = pv.z * (mx.z - mn.z) + mn.z;
      xv.w = pv.w * (mx.w - mn.w) + mn.w;
    }
    *(float4*)(xsf + b_l * 8 + fq * 4) = xv;
  } else {
    int idx2 = tid - 256;
    int gc = idx2 >> 1, half = idx2 & 1;
    int grow = ((gc >> 5) << 8) + c0 + (gc & 31);
    *(float4*)(wisf + gc * 8 + half * 4) =
        *(const float4*)(W_ih + ((size_t)v * G_ + grow) * F_ + half * 4);
  }
  if (tid < 128) {
    int grow = ((tid >> 5) << 8) + c0 + (tid & 31);
    bsumf[tid] = b_ih[v * G_ + grow] + b_hh[v * G_ + grow];
  }

  const bool hasK = (MODE == 1) || (t > 0);

  auto stageAB = [&](int ks, int bufn) {
    int kc = ks * 32;
    int row = tid >> 2, g2 = tid & 3;
    int kb = ((g2 ^ ((row >> 1) & 3)) << 4);
    // B (weights): row -> grow = (row>>5)*256 + c0 + (row&31)
    size_t boff = ((((size_t)v * G_ + ((row >> 5) << 8) + c0 + (row & 31)) * H_ + kc) << 1) + kb;
    load16((const char*)WhhHi + boff, smem + 32768 + bufn * 8192 + tid * 16);
    load16((const char*)WhhLo + boff, smem + 49152 + bufn * 8192 + tid * 16);
    // A: row -> batch b0+row
    if (MODE == 0) {
      size_t offH = ((((size_t)(v * B_ + b0 + row)) * T_ + (t - 1)) * H_ + kc) * 2 + kb;
      size_t offL = (((size_t)(v * B_ + b0 + row)) * H_ + kc) * 2 + kb;
      load16((const char*)enc + offH,   smem + bufn * 8192 + tid * 16);
      load16((const char*)hloIn + offL, smem + 16384 + bufn * 8192 + tid * 16);
    } else {
      size_t offA = (((size_t)(v * B_ + b0 + row)) * H_ + kc) * 2 + kb;
      load16((const char*)aHi + offA, smem + bufn * 8192 + tid * 16);
      load16((const char*)aLo + offA, smem + 16384 + bufn * 8192 + tid * 16);
    }
  };

  f32x4 acc[2][4];
  #pragma unroll
  for (int i = 0; i < 2; ++i)
    #pragma unroll
    for (int g = 0; g < 4; ++g) acc[i][g] = f32x4{0.f, 0.f, 0.f, 0.f};

  if (hasK) stageAB(0, 0);
  __syncthreads();   // covers xs/wis/bsum too

  if (hasK) {
    int rA = lane & 15, kg = lane >> 4;
    int ar0 = wr * 32 + rA;                       // A frag i=0 row; i=1: +16 (same swz)
    int aoff0 = ar0 * 64 + ((kg ^ ((ar0 >> 1) & 3)) << 4);
    int br0 = wc * 16 + rA;                       // B frag g=0 row; g: +g*32 (same swz)
    int boff0 = br0 * 64 + ((kg ^ ((br0 >> 1) & 3)) << 4);
    int buf = 0;
    for (int ks = 0; ks < 8; ++ks) {
      if (ks < 7) stageAB(ks + 1, buf ^ 1);
      const char* Ah = smem + buf * 8192;
      const char* Al = smem + 16384 + buf * 8192;
      const char* Bh = smem + 32768 + buf * 8192;
      const char* Bl = smem + 49152 + buf * 8192;
      bf16x8 ah0 = *(const bf16x8*)(Ah + aoff0);
      bf16x8 ah1 = *(const bf16x8*)(Ah + aoff0 + 1024);
      bf16x8 al0 = *(const bf16x8*)(Al + aoff0);
      bf16x8 al1 = *(const bf16x8*)(Al + aoff0 + 1024);
      bf16x8 bh[4], bl[4];
      #pragma unroll
      for (int g = 0; g < 4; ++g) {
        bh[g] = *(const bf16x8*)(Bh + boff0 + g * 2048);
        bl[g] = *(const bf16x8*)(Bl + boff0 + g * 2048);
      }
      #pragma unroll
      for (int g = 0; g < 4; ++g) {
        acc[0][g] = mfma16(ah0, bh[g], acc[0][g]);
        acc[1][g] = mfma16(ah1, bh[g], acc[1][g]);
      }
      #pragma unroll
      for (int g = 0; g < 4; ++g) {
        acc[0][g] = mfma16(al0, bh[g], acc[0][g]);
        acc[1][g] = mfma16(al1, bh[g], acc[1][g]);
      }
      #pragma unroll
      for (int g = 0; g < 4; ++g) {
        acc[0][g] = mfma16(ah0, bl[g], acc[0][g]);
        acc[1][g] = mfma16(ah1, bl[g], acc[1][g]);
      }
      __syncthreads();
      buf ^= 1;
    }
  }

  // ---- epilogue: + W_ih*x + bias, LSTM pointwise fully in registers ----
  {
    int rA = lane & 15;
    int cc = wc * 16 + rA;            // 0..31
    int col = c0 + cc;
    float bs[4], wr8[4][8];
    #pragma unroll
    for (int g = 0; g < 4; ++g) {
      int gc = g * 32 + cc;
      bs[g] = bsumf[gc];
      #pragma unroll
      for (int f = 0; f < 8; ++f) wr8[g][f] = wisf[gc * 8 + f];
    }
    int rowg = (lane >> 4) * 4;
    #pragma unroll
    for (int i = 0; i < 2; ++i) {
      #pragma unroll
      for (int r = 0; r < 4; ++r) {
        int b_l = wr * 32 + i * 16 + rowg + r;
        const float* xf = xsf + b_l * 8;
        float s[4];
        #pragma unroll
        for (int g = 0; g < 4; ++g) {
          float sv = acc[i][g][r] + bs[g];
          #pragma unroll
          for (int f = 0; f < 8; ++f) sv = fmaf(wr8[g][f], xf[f], sv);
          s[g] = sv;
        }
        size_t gidx = ((size_t)(v * B_ + b0 + b_l)) * H_ + col;
        float cold = cbuf[gidx];
        float cn = sigm(s[1]) * cold + sigm(s[0]) * tanhf(s[2]);
        float hn = sigm(s[3]) * tanhf(cn);
        cbuf[gidx] = cn;
        u16 hi, lo; split2(hn, hi, lo);
        if (MODE == 0) {
          enc[(((size_t)(v * B_ + b0 + b_l)) * T_ + t) * H_ + col] = hi;
          hloOut[gidx] = lo;
        } else {
          hdecHi[gidx] = hi;
          hdecLo[gidx] = lo;
        }
      }
    }
  }
}

// ---------------- decoder attention: LDS-staged enc, score -> softmax -> cv ----------------
// one block per (v,b); enc tile (64x256 bf16 = 32 KB) read from L3 ONCE via
// global_load_lds, consumed twice from LDS (score + cv).
__global__ __launch_bounds__(256) void attn_kernel(
    const u16* __restrict__ enc, const u16* __restrict__ hHi, const u16* __restrict__ hLo,
    const float* __restrict__ mask, u16* __restrict__ cvHi, u16* __restrict__ cvLo)
{
  __shared__ u16 et[T_ * H_];     // 32 KB, linear
  __shared__ float hh[H_];
  __shared__ float ss[T_];
  int bx = blockIdx.x;
  int v = bx >> 8, b = bx & 255;
  int tid = threadIdx.x;

  const char* erow = (const char*)(enc + ((size_t)(v * B_ + b)) * T_ * H_);
  #pragma unroll
  for (int it2 = 0; it2 < 8; ++it2) {
    int gidx = it2 * 256 + tid;          // 2048 granules of 16B
    load16(erow + gidx * 16, (char*)et + gidx * 16);
  }
  {
    size_t hidx = ((size_t)v * B_ + b) * H_ + tid;
    hh[tid] = bf2f(hHi[hidx]) + bf2f(hLo[hidx]);
  }
  __syncthreads();

  int t = tid >> 2, part = tid & 3;
  const u16* ep = et + t * H_ + part * 64;
  float acc = 0.f;
  #pragma unroll
  for (int it = 0; it < 8; ++it) {
    uint4 uu = *(const uint4*)(ep + it * 8);
    const float* hp = &hh[part * 64 + it * 8];
    acc = fmaf(bf2f((u16)(uu.x & 0xffff)), hp[0], acc);
    acc = fmaf(bf2f((u16)(uu.x >> 16)),    hp[1], acc);
    acc = fmaf(bf2f((u16)(uu.y & 0xffff)), hp[2], acc);
    acc = fmaf(bf2f((u16)(uu.y >> 16)),    hp[3], acc);
    acc = fmaf(bf2f((u16)(uu.z & 0xffff)), hp[4], acc);
    acc = fmaf(bf2f((u16)(uu.z >> 16)),    hp[5], acc);
    acc = fmaf(bf2f((u16)(uu.w & 0xffff)), hp[6], acc);
    acc = fmaf(bf2f((u16)(uu.w >> 16)),    hp[7], acc);
  }
  acc += __shfl_xor(acc, 1, 64);
  acc += __shfl_xor(acc, 2, 64);
  if (part == 0) ss[t] = acc * mask[((size_t)b * V_ + v) * T_ + t];
  __syncthreads();

  if (tid < 64) {
    float s = ss[tid];
    float m = s;
    #pragma unroll
    for (int d = 32; d >= 1; d >>= 1) m = fmaxf(m, __shfl_xor(m, d, 64));
    float e = __expf(s - m);
    float se = e;
    #pragma unroll
    for (int d = 32; d >= 1; d >>= 1) se += __shfl_xor(se, d, 64);
    ss[tid] = e / se;
  }
  __syncthreads();

  int j = tid;
  float a = 0.f;
  #pragma unroll 8
  for (int tt = 0; tt < T_; ++tt)
    a = fmaf(ss[tt], bf2f(et[tt * H_ + j]), a);
  u16 hi, lo; split2(a, hi, lo);
  size_t cidx = ((size_t)v * B_ + b) * H_ + j;
  cvHi[cidx] = hi;
  cvLo[cidx] = lo;
}

// ---------------- h_att = tanh(W_att . cat + b_att), split-MFMA ----------------
__global__ __launch_bounds__(256) void attg_mfma_kernel(
    const u16* __restrict__ cvHi, const u16* __restrict__ cvLo,
    const u16* __restrict__ hdHi, const u16* __restrict__ hdLo,
    const u16* __restrict__ WattHi, const u16* __restrict__ WattLo,
    const float* __restrict__ b_att,
    u16* __restrict__ hattHi, u16* __restrict__ hattLo)
{
  __shared__ char smem[40960];
  int bx = blockIdx.x;
  int v = bx >> 4, bt = (bx >> 1) & 7, nh = bx & 1;
  int bp0 = bt * 32, n0 = nh * 128;
  int tid = threadIdx.x, lane = tid & 63, w = tid >> 6;

  auto stageAB = [&](int ks, int bufn) {
    int kc = ks * 32;
    #pragma unroll
    for (int it = 0; it < 2; ++it) {
      int gb = it * 256 + tid;
      int nl = gb >> 2, g2 = gb & 3;
      int kb = ((g2 ^ ((nl >> 1) & 3)) << 4);
      size_t off = ((((size_t)v * H_ + n0 + nl) * (2 * H_) + kc) << 1) + kb;
      load16((const char*)WattHi + off, smem + 8192  + bufn * 8192 + gb * 16);
      load16((const char*)WattLo + off, smem + 24576 + bufn * 8192 + gb * 16);
    }
    {
      int g = tid & 127;
      int b = g >> 2, g2 = g & 3;
      int kb = ((g2 ^ ((b >> 1) & 3)) << 4);
      int bp = bp0 + b;
      const u16* baseH = (bp < 128) ? (cvHi + ((size_t)v * B_ + 2 * bp) * H_)
                                    : (hdHi + ((size_t)v * B_ + 2 * (bp - 128)) * H_);
      const u16* baseL = (bp < 128) ? (cvLo + ((size_t)v * B_ + 2 * bp) * H_)
                                    : (hdLo + ((size_t)v * B_ + 2 * (bp - 128)) * H_);
      if (tid < 128) load16((const char*)baseH + kc * 2 + kb, smem + bufn * 2048 + g * 16);
      else           load16((const char*)baseL + kc * 2 + kb, smem + 4096 + bufn * 2048 + g * 16);
    }
  };

  f32x4 acc[2][2];
  #pragma unroll
  for (int i = 0; i < 2; ++i)
    #pragma unroll
    for (int j = 0; j < 2; ++j) acc[i][j] = f32x4{0.f, 0.f, 0.f, 0.f};

  stageAB(0, 0);
  __syncthreads();

  int rA = lane & 15, kg = lane >> 4;
  int aoff0 = rA * 64 + ((kg ^ ((rA >> 1) & 3)) << 4);
  int gc0 = w * 32 + rA;
  int boff0 = gc0 * 64 + ((kg ^ ((gc0 >> 1) & 3)) << 4);
  int buf = 0;
  for (int ks = 0; ks < 16; ++ks) {
    if (ks < 15) stageAB(ks + 1, buf ^ 1);
    const char* Ah = smem + buf * 2048;
    const char* Al = smem + 4096  + buf * 2048;
    const char* Bh = smem + 8192  + buf * 8192;
    const char* Bl = smem + 24576 + buf * 8192;
    bf16x8 ah0 = *(const bf16x8*)(Ah + aoff0);
    bf16x8 ah1 = *(const bf16x8*)(Ah + aoff0 + 1024);
    bf16x8 al0 = *(const bf16x8*)(Al + aoff0);
    bf16x8 al1 = *(const bf16x8*)(Al + aoff0 + 1024);
    bf16x8 bh0 = *(const bf16x8*)(Bh + boff0);
    bf16x8 bh1 = *(const bf16x8*)(Bh + boff0 + 1024);
    bf16x8 bl0 = *(const bf16x8*)(Bl + boff0);
    bf16x8 bl1 = *(const bf16x8*)(Bl + boff0 + 1024);
    acc[0][0] = mfma16(ah0, bh0, acc[0][0]);
    acc[0][1] = mfma16(ah0, bh1, acc[0][1]);
    acc[1][0] = mfma16(ah1, bh0, acc[1][0]);
    acc[1][1] = mfma16(ah1, bh1, acc[1][1]);
    acc[0][0] = mfma16(al0, bh0, acc[0][0]);
    acc[0][1] = mfma16(al0, bh1, acc[0][1]);
    acc[1][0] = mfma16(al1, bh0, acc[1][0]);
    acc[1][1] = mfma16(al1, bh1, acc[1][1]);
    acc[0][0] = mfma16(ah0, bl0, acc[0][0]);
    acc[0][1] = mfma16(ah0, bl1, acc[0][1]);
    acc[1][0] = mfma16(ah1, bl0, acc[1][0]);
    acc[1][1] = mfma16(ah1, bl1, acc[1][1]);
    __syncthreads();
    buf ^= 1;
  }

  int rowg = (lane >> 4) * 4;
  #pragma unroll
  for (int i = 0; i < 2; ++i)
    #pragma unroll
    for (int j = 0; j < 2; ++j) {
      int n = n0 + w * 32 + j * 16 + rA;
      float bias = b_att[v * H_ + n];
      #pragma unroll
      for (int r = 0; r < 4; ++r) {
        int bp = bp0 + i * 16 + rowg + r;
        float tv = tanhf(acc[i][j][r] + bias);
        u16 hi, lo; split2(tv, hi, lo);
        size_t hidx = ((size_t)v * B_ + bp) * H_ + n;
        hattHi[hidx] = hi;
        hattLo[hidx] = lo;
      }
    }
}

// ---------------- output projection + clip + prev update ----------------
__global__ __launch_bounds__(256) void out_kernel(
    const u16* __restrict__ hHi, const u16* __restrict__ hLo,
    const float* __restrict__ W_out, const float* __restrict__ b_out,
    float* __restrict__ prev, float* __restrict__ out, int p)
{
  int gid = blockIdx.x * 256 + threadIdx.x;   // V*B*F = 32768
  int row = gid >> 3;
  int f = gid & 7;
  int v = row >> 8, b = row & 255;
  const u16* hp = hHi + (size_t)row * H_;
  const u16* lp = hLo + (size_t)row * H_;
  const float* wp = W_out + f * H_;
  float acc = 0.f;
  #pragma unroll 4
  for (int k = 0; k < H_; k += 8) {
    uint4 hv = *(const uint4*)(hp + k);
    uint4 lv = *(const uint4*)(lp + k);
    float4 w0 = *(const float4*)(wp + k);
    float4 w1 = *(const float4*)(wp + k + 4);
    acc = fmaf(bf2f((u16)(hv.x & 0xffff)) + bf2f((u16)(lv.x & 0xffff)), w0.x, acc);
    acc = fmaf(bf2f((u16)(hv.x >> 16))    + bf2f((u16)(lv.x >> 16)),    w0.y, acc);
    acc = fmaf(bf2f((u16)(hv.y & 0xffff)) + bf2f((u16)(lv.y & 0xffff)), w0.z, acc);
    acc = fmaf(bf2f((u16)(hv.y >> 16))    + bf2f((u16)(lv.y >> 16)),    w0.w, acc);
    acc = fmaf(bf2f((u16)(hv.z & 0xffff)) + bf2f((u16)(lv.z & 0xffff)), w1.x, acc);
    acc = fmaf(bf2f((u16)(hv.z >> 16))    + bf2f((u16)(lv.z >> 16)),    w1.y, acc);
    acc = fmaf(bf2f((u16)(hv.w & 0xffff)) + bf2f((u16)(lv.w & 0xffff)), w1.z, acc);
    acc = fmaf(bf2f((u16)(hv.w >> 16))    + bf2f((u16)(lv.w >> 16)),    w1.w, acc);
  }
  float o = fmaxf(acc + b_out[f], 0.f);
  prev[gid] = o;
  if (f < 4)
    out[(((size_t)b * V_ + v) * P_ + p) * 4 + f] = fminf(o, 1.f);
}

}  // namespace

extern "C" void kernel_launch(void* const* d_in, const int* in_sizes, int n_in,
                              void* d_out, int out_size, void* d_ws, size_t ws_size,
                              hipStream_t stream)
{
  const float* seq   = (const float*)d_in[0];
  const float* smask = (const float*)d_in[4];
  const float* maxv  = (const float*)d_in[5];
  const float* minv  = (const float*)d_in[6];
  const float* W_ih  = (const float*)d_in[7];
  const float* W_hh  = (const float*)d_in[8];
  const float* b_ih  = (const float*)d_in[9];
  const float* b_hh  = (const float*)d_in[10];
  const float* W_att = (const float*)d_in[11];
  const float* b_att = (const float*)d_in[12];
  const float* W_out = (const float*)d_in[13];
  const float* b_out = (const float*)d_in[14];
  float* out = (float*)d_out;

  char* ws = (char*)d_ws;
  float* c     = (float*)(ws);                 //  4,194,304
  float* prev  = (float*)(ws + 4194304);       //    131,072
  u16* h_lo    = (u16*)(ws + 4325376);         //  4,194,304 (2 bufs)
  u16* hdecHi  = (u16*)(ws + 8519680);         //  2,097,152
  u16* hdecLo  = (u16*)(ws + 10616832);        //  2,097,152
  u16* hattHi  = (u16*)(ws + 12713984);        //  2,097,152
  u16* hattLo  = (u16*)(ws + 14811136);        //  2,097,152
  u16* cvHi    = (u16*)(ws + 16908288);        //  2,097,152
  u16* cvLo    = (u16*)(ws + 19005440);        //  2,097,152
  u16* whhHi   = (u16*)(ws + 21102592);        //  8,388,608
  u16* whhLo   = (u16*)(ws + 29491200);        //  8,388,608
  u16* wattHi  = (u16*)(ws + 37879808);        //  4,194,304
  u16* wattLo  = (u16*)(ws + 42074112);        //  4,194,304
  u16* enc     = (u16*)(ws + 46268416);        // 134,217,728

  const size_t SZ = (size_t)V_ * B_ * H_;

  init_kernel<<<1024, 256, 0, stream>>>(c, prev, seq);
  convert_kernel<<<6144, 256, 0, stream>>>(W_hh, W_att, whhHi, whhLo, wattHi, wattLo);

  for (int t = 0; t < T_; ++t) {
    lstm_mfma_kernel<0><<<256, 512, 0, stream>>>(seq, enc,
        h_lo + ((t + 1) & 1) * SZ, h_lo + (t & 1) * SZ,
        nullptr, nullptr, nullptr, nullptr, c, whhHi, whhLo,
        W_ih, b_ih, b_hh, nullptr, nullptr, t);
  }
  copy_h_kernel<<<512, 256, 0, stream>>>(enc, h_lo + SZ, hdecHi, hdecLo);

  for (int p = 0; p < P_; ++p) {
    attn_kernel<<<V_ * B_, 256, 0, stream>>>(enc, hdecHi, hdecLo, smask, cvHi, cvLo);
    attg_mfma_kernel<<<256, 256, 0, stream>>>(cvHi, cvLo, hdecHi, hdecLo,
        wattHi, wattLo, b_att, hattHi, hattLo);
    lstm_mfma_kernel<1><<<256, 512, 0, stream>>>(prev, nullptr, nullptr, nullptr,
        hattHi, hattLo, hdecHi, hdecLo, c, whhHi, whhLo,
        W_ih, b_ih, b_hh, maxv, minv, 1);
    out_kernel<<<128, 256, 0, stream>>>(hdecHi, hdecLo, W_out, b_out, prev, out, p);
  }
}